// Round 2
// baseline (224.144 us; speedup 1.0000x reference)
//
#include <hip/hip_runtime.h>
#include <math.h>

// ConvCaps with EM routing, fp32 I/O. b=8, h=w=16, B=32 in-caps, C=32 out-caps,
// P=4 (16 pose), K=3, stride 2 -> oh=ow=7, n = 8*7*7 = 392 positions,
// KK = 9*32 = 288 votes/position. One block per position, 512 threads.
// v = P@W recomputed per pass (W = 576 KB fp32, L2-resident).

#define NTH 512
#define KK 288
#define KT 18        // 288 / 16
#define CC 32
#define PS 16
#define EPSF 1e-8f
#define LAMF 1e-3f

extern "C" __global__ void __launch_bounds__(NTH)
convcaps_em_kernel(const float* __restrict__ x, const float* __restrict__ w,
                   const float* __restrict__ beta_a, const float* __restrict__ beta_u,
                   float* __restrict__ out)
{
  // LDS: 62,592 B total
  __shared__ float sP[KK*PS];      // poses, fp32, [k][p] flat (18432 B)
  __shared__ float sA[KK];         // a_in (1152 B)
  __shared__ float sR[KK*33];      // r / rr, padded stride 33 (38016 B)
  __shared__ float sMu[CC*17];     // mu, padded 17 (2176 B)
  __shared__ float sNI2[CC*17];    // -1/(2 sigma^2), padded (2176 B)
  __shared__ float sLs[CC];        // sum_p log sigma
  __shared__ float sLnA[CC];       // log a_out
  __shared__ float sAo[CC];        // a_out
  __shared__ float sRsum[CC];
  __shared__ float sInvR[CC];

  const int tid = threadIdx.x;
  const int n   = blockIdx.x;
  const int b   = n / 49;
  const int r49 = n - b*49;
  const int ohi = r49 / 7;
  const int owi = r49 - ohi*7;

  // input window base: x[b][ohi*2 + kh][owi*2 + kw][ch], strides 16*16*544 / 16*544 / 544
  const float* xw = x + ((size_t)b*16 + (size_t)(ohi*2))*16*544 + (size_t)(owi*2)*544;

  // ---- stage poses and activations into LDS (float4: every spatial row is 2176B-aligned) ----
  for (int idx = tid; idx < KK*PS/4; idx += NTH) {   // 1152 float4s
    const int sp  = idx >> 7;          // spatial 0..8
    const int ch4 = idx & 127;         // float4 index within 512 pose floats
    const int kh = sp/3, kw = sp - kh*3;
    const float4 v = *(const float4*)&xw[kh*(16*544) + kw*544 + ch4*4];
    *(float4*)&sP[sp*512 + ch4*4] = v;
  }
  for (int idx = tid; idx < KK/4; idx += NTH) {      // 72 float4s of a_in
    const int sp  = idx / 8;
    const int bc4 = idx - sp*8;
    const int kh = sp/3, kw = sp - kh*3;
    const float4 v = *(const float4*)&xw[kh*(16*544) + kw*544 + 512 + bc4*4];
    *(float4*)&sA[sp*32 + bc4*4] = v;
  }
  for (int idx = tid; idx < KK*CC; idx += NTH)
    sR[(idx>>5)*33 + (idx&31)] = 1.0f/32.0f;
  __syncthreads();

  const int c1  = tid >> 4;   // pass-1 layout: c*16 + k_sub (k-reduce in-wave)
  const int ks1 = tid & 15;
  const int c2  = tid & 31;   // pass-2 layout: k_sub*32 + c (c-softmax in-wave)
  const int ks2 = tid >> 5;

  for (int it = 0; it < 3; ++it) {
    // ---- pre A: rr = r*a_in, normalized over c (32-lane butterflies) ----
    for (int k = ks2; k < KK; k += 16) {
      float v = sR[k*33 + c2] * sA[k];
      float s = v;
      s += __shfl_xor(s, 1);  s += __shfl_xor(s, 2);  s += __shfl_xor(s, 4);
      s += __shfl_xor(s, 8);  s += __shfl_xor(s, 16);
      sR[k*33 + c2] = v / (s + EPSF);
    }
    __syncthreads();

    // ---- pre B: r_sum[c] = sum_k rr  (16-lane butterflies over k_sub) ----
    {
      float s = 0.f;
      for (int kt = 0; kt < KT; ++kt) s += sR[(kt*16 + ks1)*33 + c1];
      s += __shfl_xor(s, 1);  s += __shfl_xor(s, 2);
      s += __shfl_xor(s, 4);  s += __shfl_xor(s, 8);
      if (ks1 == 0) { sRsum[c1] = s; sInvR[c1] = 1.f/(s + EPSF); }
    }
    __syncthreads();

    // ---- pass 1: fused mu / sigma moments (s0, s1, s2) ----
    float s0 = 0.f, s1[PS], s2[PS];
#pragma unroll
    for (int p = 0; p < PS; ++p) { s1[p] = 0.f; s2[p] = 0.f; }
    const float invr = sInvR[c1];
    for (int kt = 0; kt < KT; ++kt) {
      const int k = kt*16 + ks1;
      const float4* wg = (const float4*)(w + (((size_t)(k*32 + c1)) << 4));
      const float4 w0 = wg[0], w1 = wg[1], w2 = wg[2], w3 = wg[3];
      const float W[16] = {w0.x,w0.y,w0.z,w0.w, w1.x,w1.y,w1.z,w1.w,
                           w2.x,w2.y,w2.z,w2.w, w3.x,w3.y,w3.z,w3.w};
      const float4* pp = (const float4*)&sP[k*16];
      const float4 P0 = pp[0], P1 = pp[1], P2 = pp[2], P3 = pp[3];
      const float P[16] = {P0.x,P0.y,P0.z,P0.w, P1.x,P1.y,P1.z,P1.w,
                           P2.x,P2.y,P2.z,P2.w, P3.x,P3.y,P3.z,P3.w};
      const float co = sR[k*33 + c1] * invr;
      s0 += co;
#pragma unroll
      for (int i = 0; i < 4; ++i) {
#pragma unroll
        for (int l = 0; l < 4; ++l) {
          float v = fmaf(P[i*4+3], W[12+l],
                    fmaf(P[i*4+2], W[ 8+l],
                    fmaf(P[i*4+1], W[ 4+l], P[i*4]*W[l])));
          const float cv = co * v;
          s1[i*4+l] += cv;
          s2[i*4+l] = fmaf(cv, v, s2[i*4+l]);
        }
      }
    }
#pragma unroll
    for (int m = 1; m <= 8; m <<= 1) {
      s0 += __shfl_xor(s0, m);
#pragma unroll
      for (int p = 0; p < PS; ++p) {
        s1[p] += __shfl_xor(s1[p], m);
        s2[p] += __shfl_xor(s2[p], m);
      }
    }
    if (ks1 == 0) {
      const float rsum = sRsum[c1];
      float lsum = 0.f;
#pragma unroll
      for (int p = 0; p < PS; ++p) {
        const float mu  = s1[p];
        // sum coeff*(v-mu)^2 = s2 - mu^2*(2 - s0)   (since s1 == mu)
        float var = fmaxf(s2[p] - mu*mu*(2.0f - s0), 0.f) + EPSF;
        const float ls = 0.5f * logf(var);
        lsum += ls;
        sMu[c1*17 + p]  = mu;
        sNI2[c1*17 + p] = -0.5f / var;
      }
      const float bu = beta_u[c1];
      const float ba = beta_a[c1];
      const float cost = (16.f*bu + lsum) * rsum;
      const float ao = 1.f/(1.f + expf(-(LAMF*(ba - cost))));
      sAo[c1]  = ao;
      sLnA[c1] = logf(ao);
      sLs[c1]  = lsum;
    }
    __syncthreads();

    // ---- pass 2: ln_p -> softmax over c -> new r ----
    if (it < 2) {
      float mu[PS], ni2[PS];
#pragma unroll
      for (int p = 0; p < PS; ++p) { mu[p] = sMu[c2*17+p]; ni2[p] = sNI2[c2*17+p]; }
      // ln a_out - sum_p log_sigma - 16 * 0.5*ln(2*pi)
      const float lc = sLnA[c2] - sLs[c2] - 16.f*0.91893853320467274178f;
      for (int kt = 0; kt < KT; ++kt) {
        const int k = kt*16 + ks2;
        const float4* wg = (const float4*)(w + (((size_t)(k*32 + c2)) << 4));
        const float4 w0 = wg[0], w1 = wg[1], w2 = wg[2], w3 = wg[3];
        const float W[16] = {w0.x,w0.y,w0.z,w0.w, w1.x,w1.y,w1.z,w1.w,
                             w2.x,w2.y,w2.z,w2.w, w3.x,w3.y,w3.z,w3.w};
        const float4* pp = (const float4*)&sP[k*16];
        const float4 P0 = pp[0], P1 = pp[1], P2 = pp[2], P3 = pp[3];
        const float P[16] = {P0.x,P0.y,P0.z,P0.w, P1.x,P1.y,P1.z,P1.w,
                             P2.x,P2.y,P2.z,P2.w, P3.x,P3.y,P3.z,P3.w};
        float acc = 0.f;
#pragma unroll
        for (int i = 0; i < 4; ++i) {
#pragma unroll
          for (int l = 0; l < 4; ++l) {
            float v = fmaf(P[i*4+3], W[12+l],
                      fmaf(P[i*4+2], W[ 8+l],
                      fmaf(P[i*4+1], W[ 4+l], P[i*4]*W[l])));
            const float d = v - mu[i*4+l];
            acc = fmaf(d*d, ni2[i*4+l], acc);
          }
        }
        const float lnap = acc + lc;
        // softmax over c: 32-lane max + sum butterflies
        float m = lnap;
        m = fmaxf(m, __shfl_xor(m, 1));  m = fmaxf(m, __shfl_xor(m, 2));
        m = fmaxf(m, __shfl_xor(m, 4));  m = fmaxf(m, __shfl_xor(m, 8));
        m = fmaxf(m, __shfl_xor(m, 16));
        const float e = expf(lnap - m);
        float s = e;
        s += __shfl_xor(s, 1);  s += __shfl_xor(s, 2);  s += __shfl_xor(s, 4);
        s += __shfl_xor(s, 8);  s += __shfl_xor(s, 16);
        sR[k*33 + c2] = e / s;
      }
    }
    __syncthreads();
  }

  // ---- epilogue: out[n][c*16+p] = mu, out[n][512+c] = a_out ----
  {
    const size_t ob = (size_t)n * 544;
    const int ch = tid;                       // 0..511
    out[ob + ch] = sMu[(ch>>4)*17 + (ch&15)];
    if (tid < CC) out[ob + 512 + tid] = sAo[tid];
  }
}

extern "C" void kernel_launch(void* const* d_in, const int* in_sizes, int n_in,
                              void* d_out, int out_size, void* d_ws, size_t ws_size,
                              hipStream_t stream) {
  (void)in_sizes; (void)n_in; (void)d_ws; (void)ws_size; (void)out_size;
  const float* x  = (const float*)d_in[0];
  const float* w  = (const float*)d_in[1];
  const float* ba = (const float*)d_in[2];
  const float* bu = (const float*)d_in[3];
  float* out = (float*)d_out;
  convcaps_em_kernel<<<dim3(392), dim3(NTH), 0, stream>>>(x, w, ba, bu, out);
}